// Round 1
// baseline (351.809 us; speedup 1.0000x reference)
//
#include <hip/hip_runtime.h>
#include <math.h>

// ---------------------------------------------------------------------------
// S2->SO(3) spherical conv, restructured:
//   fhat[l,m>=0][b][i]  = sum_k w[k] d^l_{m,0}(beta_in_k) * DFT_j(x[b,i,k,j], m)
//   yhat[l,n][i][o]     = SCALING * sum_g kernel[i,o,g] d^l_{n,0}(GB) e^{-i n GA_g}
//   z_l[m,n]            = sum_i fhat conj(yhat)      (m>=0 only; Hermitian)
//   F_k[m,n]            = sum_l (2l+1) d^l_{m,n}(beta_out_k) z_l[m,n]
//   out[p,q]            = Re G[0,q] + 2 sum_{m=1..9} Re(e^{i pi m p/10} G[m,q])
//   G[m,q]              = sum_n F[m,n] e^{i pi n q/10}
// Constants are rebuilt on-device every launch (graph-capture safe).
// ---------------------------------------------------------------------------

// workspace layout (float offsets from base):
//   [0..119]    w[60] as double
//   FW=128      gW   [55*60]            W packed (sm-major)
//   FD=3456     gD   [20*715]           D packed (k-major)
//   FY=17792    gyhat[5*100*2] float2   (o,s,i)
//   FC=19840    gcos[20]; FS=19860 gsin[20]
//   FH=19904    gfhat[512*55*2] float2  (b, sm, i)
#define WS_FW 128
#define WS_FD 3456
#define WS_FY 17792
#define WS_FC 19840
#define WS_FS 19860
#define WS_FH 19904

__device__ __forceinline__ double ipow_d(double x, int e) {
    double r = 1.0;
    for (int i = 0; i < e; ++i) r *= x;
    return r;
}

// Wigner small-d  d^l_{mp,m}(beta), quantum norm, CS phase (matches reference).
__device__ double dsmall(int l, int mp, int m, double beta) {
    double fact[20];
    fact[0] = 1.0;
    for (int i = 1; i < 20; ++i) fact[i] = fact[i - 1] * (double)i;
    double cb = cos(0.5 * beta), sb = sin(0.5 * beta);
    double pref = sqrt(fact[l + m] * fact[l - m] * fact[l + mp] * fact[l - mp]);
    int s0 = m - mp; if (s0 < 0) s0 = 0;
    int s1 = l + m;  if (l - mp < s1) s1 = l - mp;
    double tot = 0.0;
    for (int s = s0; s <= s1; ++s) {
        double den = fact[l + m - s] * fact[s] * fact[mp - m + s] * fact[l - mp - s];
        double sgn = ((mp - m + s) & 1) ? -1.0 : 1.0;
        tot += sgn / den * ipow_d(cb, 2 * l + m - mp - 2 * s) * ipow_d(sb, mp - m + 2 * s);
    }
    return pref * tot;
}

// ---- stage A: Driscoll-Healy quadrature weights (60 doubles) ----
extern "C" __global__ void k_setup_w(float* wsf) {
    double* w = (double*)wsf;
    int t = threadIdx.x;
    if (t < 60) {
        double beta = M_PI * (2 * t + 1) / 120.0;
        double sum = 0.0;
        for (int k = 0; k < 30; ++k)
            sum += sin((double)((2 * t + 1) * (2 * k + 1)) * M_PI / 120.0) / (double)(2 * k + 1);
        w[t] = (2.0 / 30.0) * sin(beta) * sum;
    }
}

// ---- stage B: all Wigner-derived constant tables ----
extern "C" __global__ void k_setup_const(float* wsf, const float* __restrict__ kern) {
    const double* w = (const double*)wsf;
    float*  gW    = wsf + WS_FW;
    float*  gD    = wsf + WS_FD;
    float2* gyhat = (float2*)(wsf + WS_FY);
    float*  gcos  = wsf + WS_FC;
    float*  gsin  = wsf + WS_FS;
    const int base[11] = {0, 1, 7, 22, 50, 95, 161, 252, 372, 525, 715};
    const int tri[11]  = {0, 1, 3, 6, 10, 15, 21, 28, 36, 45, 55};
    int idx = blockIdx.x * 64 + threadIdx.x;
    if (idx < 3300) {                       // W packed: [sm][k]
        int sm = idx / 60, k = idx % 60;
        int l = 0; while (sm >= tri[l + 1]) ++l;
        int m = sm - tri[l];
        double beta = M_PI * (2 * k + 1) / 120.0;
        gW[idx] = (float)(w[k] * dsmall(l, m, 0, beta));
    } else if (idx < 17600) {               // D packed: [k][p], p over (l, m>=0, n)
        int i2 = idx - 3300;
        int k = i2 / 715, p = i2 % 715;
        int l = 0; while (p >= base[l + 1]) ++l;
        int r = p - base[l];
        int L = 2 * l + 1;
        int m = r / L;
        int n = r % L - l;
        double beta = M_PI * (2 * k + 1) / 40.0;
        gD[i2] = (float)((double)L * dsmall(l, m, n, beta));
    } else if (idx < 18600) {               // yhat: [o][s][i]
        int i3 = idx - 17600;
        int o = i3 / 200, r = i3 % 200;
        int s = r / 2, i = r % 2;
        int l = 0; while ((l + 1) * (l + 1) <= s) ++l;
        int n = s - l * l - l;
        double dv = dsmall(l, n, 0, M_PI / 160.0);
        const double SC = 1.0 / sqrt(6.0 * 2.0 * 10000.0 / 900.0);
        double ar = 0.0, ai = 0.0;
        for (int g = 0; g < 6; ++g) {
            double kv = (double)kern[i * 30 + o * 6 + g];
            double ang = (double)n * M_PI * (double)g / 3.0;   // n * GA_g
            ar += kv * cos(ang);
            ai -= kv * sin(ang);
        }
        gyhat[i3] = make_float2((float)(SC * dv * ar), (float)(SC * dv * ai));
    } else if (idx < 18620) {               // cos/sin(pi*t/10) tables
        int t = idx - 18600;
        gcos[t] = (float)cos(M_PI * t / 10.0);
        gsin[t] = (float)sin(M_PI * t / 10.0);
    }
}

// ---- stage C: fhat[b][sm][i] = sum_k W[sm][k] * DFT_j(x[b,i,k,j], m(sm)) ----
extern "C" __global__ void __launch_bounds__(256) k_fhat(const float* __restrict__ x, float* wsf) {
    __shared__ float  xs[3600];
    __shared__ float2 e60[60];
    __shared__ float2 Y[600];     // [k][m], m=0..9
    const float* gW = wsf + WS_FW;
    float2* gfhat = (float2*)(wsf + WS_FH);
    int bi = blockIdx.x;          // b*2 + i
    int tid = threadIdx.x;
    const float* xp = x + bi * 3600;
    for (int t = tid; t < 3600; t += 256) xs[t] = xp[t];
    if (tid < 60) {
        double a = 2.0 * M_PI * (double)tid / 60.0;
        e60[tid] = make_float2((float)cos(a), (float)(-sin(a)));   // e^{-2pi i t/60}
    }
    __syncthreads();
    for (int it = tid; it < 600; it += 256) {
        int k = it / 10, m = it % 10;
        const float* row = xs + k * 60;
        float ar = 0.f, ai = 0.f;
        int t = 0;
        for (int j = 0; j < 60; ++j) {
            float xv = row[j];
            float2 e = e60[t];
            ar += xv * e.x; ai += xv * e.y;
            t += m; if (t >= 60) t -= 60;
        }
        Y[it] = make_float2(ar, ai);
    }
    __syncthreads();
    const int tri[11] = {0, 1, 3, 6, 10, 15, 21, 28, 36, 45, 55};
    if (tid < 55) {
        int sm = tid;
        int l = 0; while (sm >= tri[l + 1]) ++l;
        int m = sm - tri[l];
        float ar = 0.f, ai = 0.f;
        for (int k = 0; k < 60; ++k) {
            float wv = gW[sm * 60 + k];
            float2 y = Y[k * 10 + m];
            ar += wv * y.x; ai += wv * y.y;
        }
        int b = bi >> 1, i = bi & 1;
        gfhat[b * 110 + sm * 2 + i] = make_float2(ar, ai);
    }
}

// ---- stage D: one block per (b,o,k): z -> F -> G -> out ----
extern "C" __global__ void __launch_bounds__(256) k_main(const float* __restrict__ wsf,
                                                         const float* __restrict__ bias,
                                                         float* __restrict__ out) {
    __shared__ float2 fb[110];    // fhat[b]  : [sm][i]
    __shared__ float2 yo[200];    // yhat[o]  : [s][i]
    __shared__ float2 zs[715];    // z packed (l, m>=0, n)
    __shared__ float  Dk[715];    // D packed for this k
    __shared__ float2 Fs[190];    // F[m 0..9][n -9..9]
    __shared__ float2 Gs[200];    // G[m 0..9][q 0..19]
    __shared__ float  ct[20], st[20];
    const float*  gD    = wsf + WS_FD;
    const float2* gyhat = (const float2*)(wsf + WS_FY);
    const float*  gcos  = wsf + WS_FC;
    const float*  gsin  = wsf + WS_FS;
    const float2* gfhat = (const float2*)(wsf + WS_FH);
    const int base[11] = {0, 1, 7, 22, 50, 95, 161, 252, 372, 525, 715};
    const int tri[10]  = {0, 1, 3, 6, 10, 15, 21, 28, 36, 45};

    int blk = blockIdx.x, tid = threadIdx.x;
    int b = blk / 100, rem = blk % 100;
    int o = rem / 20, k = rem % 20;

    if (tid < 110) fb[tid] = gfhat[b * 110 + tid];
    if (tid < 200) yo[tid] = gyhat[o * 200 + tid];
    for (int t = tid; t < 715; t += 256) Dk[t] = gD[k * 715 + t];
    if (tid < 20) { ct[tid] = gcos[tid]; st[tid] = gsin[tid]; }
    __syncthreads();

    // z_l[m,n] = sum_i fhat_l[m,i] * conj(yhat_l[n,i])
    for (int p = tid; p < 715; p += 256) {
        int l = 0; while (p >= base[l + 1]) ++l;
        int r = p - base[l];
        int L = 2 * l + 1;
        int m = r / L;
        int n = r % L - l;
        int sm = tri[l] + m;
        int sf = l * l + l + n;
        float2 f0 = fb[sm * 2],     f1 = fb[sm * 2 + 1];
        float2 y0 = yo[sf * 2],     y1 = yo[sf * 2 + 1];
        float zr = f0.x * y0.x + f0.y * y0.y + f1.x * y1.x + f1.y * y1.y;
        float zi = f0.y * y0.x - f0.x * y0.y + f1.y * y1.x - f1.x * y1.y;
        zs[p] = make_float2(zr, zi);
    }
    __syncthreads();

    // F[m,n] = sum_l D_l z_l
    if (tid < 190) {
        int m = tid / 19;
        int n = tid % 19 - 9;
        int a = n < 0 ? -n : n;
        int lmin = m > a ? m : a;
        float fr = 0.f, fi = 0.f;
        for (int l = lmin; l <= 9; ++l) {
            int p = base[l] + m * (2 * l + 1) + (n + l);
            float d = Dk[p];
            float2 zv = zs[p];
            fr += d * zv.x; fi += d * zv.y;
        }
        Fs[tid] = make_float2(fr, fi);
    }
    __syncthreads();

    // G[m,q] = sum_n F[m,n] e^{i pi n q / 10}
    if (tid < 200) {
        int m = tid / 20, q = tid % 20;
        int pi = (20 - (9 * q) % 20) % 20;   // phase index for n = -9
        float gr = 0.f, gi = 0.f;
        for (int nn = 0; nn < 19; ++nn) {
            float c = ct[pi], s = st[pi];
            float2 f = Fs[m * 19 + nn];
            gr += f.x * c - f.y * s;
            gi += f.x * s + f.y * c;
            pi += q; if (pi >= 20) pi -= 20;
        }
        Gs[tid] = make_float2(gr, gi);
    }
    __syncthreads();

    // out[p,q] = bias + Re G[0,q] + 2 sum_{m=1..9} (cos Re - sin Im)
    float bo = bias[o];
    for (int t = tid; t < 400; t += 256) {
        int pp = t / 20, q = t % 20;
        float val = bo + Gs[q].x;
        int pi = 0;
        for (int m = 1; m <= 9; ++m) {
            pi += pp; if (pi >= 20) pi -= 20;
            float2 g = Gs[m * 20 + q];
            val += 2.f * (ct[pi] * g.x - st[pi] * g.y);
        }
        out[blk * 400 + t] = val;
    }
}

extern "C" void kernel_launch(void* const* d_in, const int* in_sizes, int n_in,
                              void* d_out, int out_size, void* d_ws, size_t ws_size,
                              hipStream_t stream) {
    const float* x    = (const float*)d_in[0];
    const float* kern = (const float*)d_in[1];
    const float* bias = (const float*)d_in[2];
    float* out = (float*)d_out;
    float* wsf = (float*)d_ws;
    k_setup_w   <<<1,    64,  0, stream>>>(wsf);
    k_setup_const<<<291, 64,  0, stream>>>(wsf, kern);
    k_fhat      <<<1024, 256, 0, stream>>>(x, wsf);
    k_main      <<<51200,256, 0, stream>>>(wsf, bias, out);
}

// Round 2
// 217.503 us; speedup vs baseline: 1.6175x; 1.6175x over previous
//
#include <hip/hip_runtime.h>
#include <math.h>

// ---------------------------------------------------------------------------
// S2->SO(3) spherical conv, v2: radix-2 parity splits + k-quad blocks.
//   fhat[l,m>=0][b][i]  = sum_k w[k] d^l_{m,0}(beta_in_k) * DFT_j(x[b,i,k,j], m)
//   yhat[l,n][i][o]     = SCALING * sum_g kernel[i,o,g] d^l_{n,0}(GB) e^{-i n GA_g}
//   z[b,o][p=(l,m>=0,n)] = sum_i fhat conj(yhat)       (Hermitian half)
//   F_k[m,n] = sum_l (2l+1) d^l_{m,n}(beta_out_k) z[p]
//   G[m,q0](+/-) via n-parity split; out[p0,q](+/-) via m-parity split, Re only.
// ---------------------------------------------------------------------------

// workspace float offsets
#define WS_W    128     // gW   [k(60)][sm(55)]          3300 floats
#define WS_D    3456    // gD   [k(20)][p(715)]          14300
#define WS_Y    17760   // gyhat[o(5)][s(100)][i(2)] f2  2000 floats
#define WS_EM   19776   // gEm  [m(10)][j(60)] f2        1200
#define WS_PE   20992   // Pe(90 f2) Po(100) Ee(50) Eo(50) = 580 floats
#define WS_PACK 21600   // gPack[715] int
#define WS_FH   22336   // gfhat[b(512)][sm(55)][i(2)] f2 = 112640 floats

__device__ __forceinline__ double ipow_d(double x, int e) {
    double r = 1.0;
    for (int i = 0; i < e; ++i) r *= x;
    return r;
}

// Wigner small-d d^l_{mp,m}(beta), quantum norm, CS phase.
__device__ double dsmall(int l, int mp, int m, double beta) {
    double fact[20];
    fact[0] = 1.0;
    for (int i = 1; i < 20; ++i) fact[i] = fact[i - 1] * (double)i;
    double cb = cos(0.5 * beta), sb = sin(0.5 * beta);
    double pref = sqrt(fact[l + m] * fact[l - m] * fact[l + mp] * fact[l - mp]);
    int s0 = m - mp; if (s0 < 0) s0 = 0;
    int s1 = l + m;  if (l - mp < s1) s1 = l - mp;
    double tot = 0.0;
    for (int s = s0; s <= s1; ++s) {
        double den = fact[l + m - s] * fact[s] * fact[mp - m + s] * fact[l - mp - s];
        double sgn = ((mp - m + s) & 1) ? -1.0 : 1.0;
        tot += sgn / den * ipow_d(cb, 2 * l + m - mp - 2 * s) * ipow_d(sb, mp - m + 2 * s);
    }
    return pref * tot;
}

extern "C" __global__ void k_setup_w(float* wsf) {
    double* w = (double*)wsf;
    int t = threadIdx.x;
    if (t < 60) {
        double beta = M_PI * (2 * t + 1) / 120.0;
        double sum = 0.0;
        for (int k = 0; k < 30; ++k)
            sum += sin((double)((2 * t + 1) * (2 * k + 1)) * M_PI / 120.0) / (double)(2 * k + 1);
        w[t] = (2.0 / 30.0) * sin(beta) * sum;
    }
}

extern "C" __global__ void k_setup_const(float* wsf, const float* __restrict__ kern) {
    const double* w = (const double*)wsf;
    const int tri[11] = {0, 1, 3, 6, 10, 15, 21, 28, 36, 45, 55};
    int idx = blockIdx.x * 64 + threadIdx.x;
    if (idx < 3300) {                       // gW transposed [k][sm]
        int k = idx / 55, smi = idx % 55;
        int l = 0; while (smi >= tri[l + 1]) ++l;
        int m = smi - tri[l];
        double beta = M_PI * (2 * k + 1) / 120.0;
        wsf[WS_W + idx] = (float)(w[k] * dsmall(l, m, 0, beta));
    } else if (idx < 17600) {               // gD [k][p]
        int i2 = idx - 3300;
        int k = i2 / 715, p = i2 % 715;
        int l = 0, bcur = 0;
        for (;;) { int bs = (l + 1) * (2 * l + 1); if (p < bcur + bs) break; bcur += bs; ++l; }
        int r = p - bcur; int L = 2 * l + 1;
        int m = r / L; int n = r % L - l;
        double beta = M_PI * (2 * k + 1) / 40.0;
        wsf[WS_D + i2] = (float)((double)L * dsmall(l, m, n, beta));
    } else if (idx < 18600) {               // gyhat [o][s][i]
        int i3 = idx - 17600;
        int o = i3 / 200, r5 = i3 % 200;
        int s = r5 / 2, i = r5 % 2;
        int l = 0; while ((l + 1) * (l + 1) <= s) ++l;
        int n = s - l * l - l;
        double dv = dsmall(l, n, 0, M_PI / 160.0);
        const double SC = 1.0 / sqrt(6.0 * 2.0 * 10000.0 / 900.0);
        double ar = 0.0, ai = 0.0;
        for (int g = 0; g < 6; ++g) {
            double kv = (double)kern[i * 30 + o * 6 + g];
            double ang = (double)n * M_PI * (double)g / 3.0;
            ar += kv * cos(ang);
            ai -= kv * sin(ang);
        }
        ((float2*)(wsf + WS_Y))[i3] = make_float2((float)(SC * dv * ar), (float)(SC * dv * ai));
    } else if (idx < 19200) {               // gEm [m][j]: e^{-2pi i m j/60}
        int t = idx - 18600; int m = t / 60, j = t % 60;
        double a = 2.0 * M_PI * (double)(m * j) / 60.0;
        ((float2*)(wsf + WS_EM))[t] = make_float2((float)cos(a), (float)(-sin(a)));
    } else if (idx < 19290) {               // Pe[q0][t]: n=2t-8
        int t = idx - 19200; int q0 = t / 9; int n = 2 * (t % 9) - 8;
        double a = M_PI * (double)(n * q0) / 10.0;
        ((float2*)(wsf + WS_PE))[t] = make_float2((float)cos(a), (float)sin(a));
    } else if (idx < 19390) {               // Po[q0][t]: n=2t-9
        int t = idx - 19290; int q0 = t / 10; int n = 2 * (t % 10) - 9;
        double a = M_PI * (double)(n * q0) / 10.0;
        ((float2*)(wsf + WS_PE))[90 + t] = make_float2((float)cos(a), (float)sin(a));
    } else if (idx < 19440) {               // Ee[p0][me]: m=2me, w=1 for m==0 else 2
        int t = idx - 19390; int p0 = t / 5; int m = 2 * (t % 5);
        double wt = (m == 0) ? 1.0 : 2.0;
        double a = M_PI * (double)(m * p0) / 10.0;
        ((float2*)(wsf + WS_PE))[190 + t] = make_float2((float)(wt * cos(a)), (float)(wt * sin(a)));
    } else if (idx < 19490) {               // Eo[p0][mo]: m=2mo+1, w=2
        int t = idx - 19440; int p0 = t / 5; int m = 2 * (t % 5) + 1;
        double a = M_PI * (double)(m * p0) / 10.0;
        ((float2*)(wsf + WS_PE))[240 + t] = make_float2((float)(2.0 * cos(a)), (float)(2.0 * sin(a)));
    } else if (idx < 20205) {               // gPack[p] = sm*128 + sf
        int p = idx - 19490;
        int l = 0, bcur = 0;
        for (;;) { int bs = (l + 1) * (2 * l + 1); if (p < bcur + bs) break; bcur += bs; ++l; }
        int r = p - bcur; int L = 2 * l + 1;
        int m = r / L; int n = r % L - l;
        int smi = tri[l] + m; int sf = l * l + l + n;
        ((int*)(wsf + WS_PACK))[p] = smi * 128 + sf;
    }
}

// ---- fhat: block per (b,i) ----
extern "C" __global__ void __launch_bounds__(256) k_fhat(const float* __restrict__ x,
                                                          float* __restrict__ wsf) {
    __shared__ float  xs[3600];
    __shared__ float2 ems[610];   // [m][61] padded (conflict-free)
    __shared__ float2 Y[600];     // [k][m]
    int tid = threadIdx.x;
    int bi = blockIdx.x;
    const float4* xp = (const float4*)(x + bi * 3600);
    for (int t = tid; t < 900; t += 256) ((float4*)xs)[t] = xp[t];
    const float2* gEm = (const float2*)(wsf + WS_EM);
    for (int t = tid; t < 600; t += 256) {
        int m = t / 60, j = t - m * 60;
        ems[m * 61 + j] = gEm[t];
    }
    __syncthreads();
    for (int it = tid; it < 600; it += 256) {
        int k = it / 10, m = it - k * 10;
        const float*  row = xs + k * 60;
        const float2* em  = ems + m * 61;
        float ar = 0.f, ai = 0.f;
        #pragma unroll 12
        for (int j = 0; j < 60; ++j) {
            float xv = row[j];
            float2 e = em[j];
            ar += xv * e.x; ai += xv * e.y;
        }
        Y[it] = make_float2(ar, ai);
    }
    __syncthreads();
    if (tid < 55) {
        int smi = tid;
        const int tri[11] = {0, 1, 3, 6, 10, 15, 21, 28, 36, 45, 55};
        int l = 0; while (smi >= tri[l + 1]) ++l;
        int m = smi - tri[l];
        const float* gW = wsf + WS_W;
        float ar = 0.f, ai = 0.f;
        for (int kk = 0; kk < 60; ++kk) {
            float wv = gW[kk * 55 + smi];
            float2 y = Y[kk * 10 + m];
            ar += wv * y.x; ai += wv * y.y;
        }
        int b = bi >> 1, i = bi & 1;
        ((float2*)(wsf + WS_FH))[b * 110 + smi * 2 + i] = make_float2(ar, ai);
    }
}

// ---- main: block per (b, o, k-quad) ----
extern "C" __global__ void __launch_bounds__(256) k_main(const float* __restrict__ wsf,
                                                          const float* __restrict__ bias,
                                                          float* __restrict__ out) {
    __shared__ float sm_[5132];
    // float offsets: z 0..1429 | F 1432..2951 (4x190 f2) | G 2952..4551 (4x200 f2,
    // aliases fb@2952(220)+yo@3172(400)) | tables 4552..5131
    const int S_Z = 0, S_F = 1432, S_G = 2952, S_FB = 2952, S_YO = 3172, S_T = 4552;
    int tid = threadIdx.x;
    int blk = blockIdx.x;
    int b = blk / 25; int r = blk - b * 25; int o = r / 5; int k0 = (r - o * 5) * 4;

    const float2* gfb = (const float2*)(wsf + WS_FH) + b * 110;
    for (int t = tid; t < 110; t += 256) ((float2*)(sm_ + S_FB))[t] = gfb[t];
    const float2* gyo = (const float2*)(wsf + WS_Y) + o * 200;
    for (int t = tid; t < 200; t += 256) ((float2*)(sm_ + S_YO))[t] = gyo[t];
    const float2* gT = (const float2*)(wsf + WS_PE);
    for (int t = tid; t < 290; t += 256) ((float2*)(sm_ + S_T))[t] = gT[t];
    __syncthreads();

    // z[p] = sum_i fhat * conj(yhat)
    const int* gPack = (const int*)(wsf + WS_PACK);
    for (int p = tid; p < 715; p += 256) {
        int pk = gPack[p];
        int smi = pk >> 7, sf = pk & 127;
        float4 f = *(const float4*)(sm_ + S_FB + smi * 4);
        float4 y = *(const float4*)(sm_ + S_YO + sf * 4);
        float zr = f.x * y.x + f.y * y.y + f.z * y.z + f.w * y.w;
        float zi = f.y * y.x - f.x * y.y + f.w * y.z - f.z * y.w;
        ((float2*)(sm_ + S_Z))[p] = make_float2(zr, zi);
    }
    __syncthreads();

    // F[kl][m,n] = sum_l D z   (parity-split storage: Fe f2[0..89], Fo f2[90..189])
    const float* gD = wsf + WS_D;
    for (int t = tid; t < 760; t += 256) {
        int kl = t / 190; int r2 = t - kl * 190;
        int m = r2 / 19;  int nn = r2 - m * 19;
        int n = nn - 9;
        int a = n < 0 ? -n : n;
        int lmin = m > a ? m : a;
        int tL = lmin * (lmin - 1);
        int base = tL * (2 * lmin - 1) / 3 + ((3 * tL) >> 1) + lmin;
        int p = base + m * (2 * lmin + 1) + n + lmin;
        const float* Dk = gD + (k0 + kl) * 715;
        float fr = 0.f, fi = 0.f;
        for (int l = lmin; l <= 9; ++l) {
            float d = Dk[p];
            float2 zv = ((const float2*)(sm_ + S_Z))[p];
            fr += d * zv.x; fi += d * zv.y;
            p += (l + 1) * (2 * l + 1) + 2 * m + 1;
        }
        float2* Fb = (float2*)(sm_ + S_F + kl * 380);
        int idx = (nn & 1) ? (m * 9 + (nn >> 1)) : (90 + m * 10 + (nn >> 1));
        Fb[idx] = make_float2(fr, fi);
    }
    __syncthreads();

    // G[m,q0], G[m,q0+10] = Ge +/- Go  (stored split by m parity: Ge2[me][q], Go2[mo][q])
    for (int t = tid; t < 400; t += 256) {
        int kl = t / 100; int r3 = t - kl * 100;
        int m = r3 / 10;  int q0 = r3 - m * 10;
        const float2* F2 = (const float2*)(sm_ + S_F + kl * 380);
        const float2* Pe = (const float2*)(sm_ + S_T) + q0 * 9;
        const float2* Po = (const float2*)(sm_ + S_T + 180) + q0 * 10;
        const float2* Fe = F2 + m * 9;
        const float2* Fo = F2 + 90 + m * 10;
        float ger = 0.f, gei = 0.f, gor_ = 0.f, goi = 0.f;
        #pragma unroll
        for (int tt = 0; tt < 9; ++tt) {
            float2 f = Fe[tt], pz = Pe[tt];
            ger += f.x * pz.x - f.y * pz.y;
            gei += f.x * pz.y + f.y * pz.x;
        }
        #pragma unroll
        for (int tt = 0; tt < 10; ++tt) {
            float2 f = Fo[tt], pz = Po[tt];
            gor_ += f.x * pz.x - f.y * pz.y;
            goi += f.x * pz.y + f.y * pz.x;
        }
        float2* Gb = (float2*)(sm_ + S_G) + kl * 200;
        int half = (m & 1) ? 100 : 0;
        int mh = m >> 1;
        Gb[half + mh * 20 + q0]      = make_float2(ger + gor_, gei + goi);
        Gb[half + mh * 20 + q0 + 10] = make_float2(ger - gor_, gei - goi);
    }
    __syncthreads();

    // out[p0,q] = bias + Ae + Ao ; out[p0+10,q] = bias + Ae - Ao   (Re only)
    float bo = bias[o];
    for (int t = tid; t < 800; t += 256) {
        int kl = t / 200; int r4 = t - kl * 200;
        int p0 = r4 / 20; int q = r4 - p0 * 20;
        const float2* Gb = (const float2*)(sm_ + S_G) + kl * 200;
        const float2* Ee = (const float2*)(sm_ + S_T + 380) + p0 * 5;
        const float2* Eo = (const float2*)(sm_ + S_T + 480) + p0 * 5;
        float ae = 0.f, ao = 0.f;
        #pragma unroll
        for (int me = 0; me < 5; ++me) {
            float2 e = Ee[me], g = Gb[me * 20 + q];
            ae += e.x * g.x - e.y * g.y;
            float2 e2 = Eo[me], g2 = Gb[100 + me * 20 + q];
            ao += e2.x * g2.x - e2.y * g2.y;
        }
        float* op = out + (((b * 5 + o) * 20 + (k0 + kl)) * 400 + p0 * 20 + q);
        op[0]   = bo + ae + ao;
        op[200] = bo + ae - ao;
    }
}

extern "C" void kernel_launch(void* const* d_in, const int* in_sizes, int n_in,
                              void* d_out, int out_size, void* d_ws, size_t ws_size,
                              hipStream_t stream) {
    const float* x    = (const float*)d_in[0];
    const float* kern = (const float*)d_in[1];
    const float* bias = (const float*)d_in[2];
    float* out = (float*)d_out;
    float* wsf = (float*)d_ws;
    k_setup_w    <<<1,     64,  0, stream>>>(wsf);
    k_setup_const<<<316,   64,  0, stream>>>(wsf, kern);
    k_fhat       <<<1024,  256, 0, stream>>>(x, wsf);
    k_main       <<<12800, 256, 0, stream>>>(wsf, bias, out);
}